// Round 9
// baseline (114.116 us; speedup 1.0000x reference)
//
#include <hip/hip_runtime.h>
#include <hip/hip_fp16.h>
#include <math.h>

constexpr int N = 100000;   // nodes
constexpr int E = 1600000;  // edges
constexpr int F = 32;       // F_IN == HIDDEN
constexpr int C = 2;        // classes

constexpr int NBUCK = (N + 511) >> 9;           // 196 buckets of 512 dst nodes
constexpr int CAPB  = 10240;                    // padded per-bucket capacity
                                                // (mean 8163, sigma ~90 -> +23 sigma)
constexpr int CHUNK = 8192;                     // edges per redistribution WG
constexpr int NCHUNK = (E + CHUNK - 1) / CHUNK; // 196
constexpr int SPLIT = 50000;                    // agg1 cache-blocking split (3.2MB halves)

__device__ __forceinline__ int get_src(const int* ei, int e, int f64) {
    return f64 ? ei[2 * e] : ei[e];
}
__device__ __forceinline__ int get_dst(const int* ei, int e, int f64) {
    return f64 ? ei[2 * (E + e)] : ei[E + e];
}

// ---------------------------------------------------------------------------
// Bucket redistribution with built-in int64/int32 layout probe (all-zero odd
// dwords over 2048 samples <=> int64 little-endian; impossible for random
// int32 in [0,100000)). Chunk staged in LDS; one global atomic per
// (WG, bucket); writes form ~196 sequential streams into padded bucket slots.
// ---------------------------------------------------------------------------
__global__ void k_bucket(const int* __restrict__ ei, int* __restrict__ bcursor,
                         int* __restrict__ epk) {
    __shared__ int h[NBUCK];
    __shared__ int base[NBUCK];
    __shared__ int sS[CHUNK];
    __shared__ int sD[CHUNK];
    __shared__ int sflag;
    int tid = threadIdx.x;
    if (tid == 0) sflag = 0;
    for (int i = tid; i < NBUCK; i += blockDim.x) h[i] = 0;
    __syncthreads();
    int accf = 0;
    for (int i = tid; i < 2048; i += blockDim.x) accf |= ei[2 * i + 1];
    if (accf) atomicOr(&sflag, 1);
    __syncthreads();
    int f64 = sflag ? 0 : 1;
    int e0 = blockIdx.x * CHUNK;
    int ne = min(E - e0, CHUNK);
    for (int i = tid; i < ne; i += blockDim.x) {
        int s = get_src(ei, e0 + i, f64);
        int d = get_dst(ei, e0 + i, f64);
        sS[i] = s;
        sD[i] = d;
        atomicAdd(&h[d >> 9], 1);
    }
    __syncthreads();
    for (int b = tid; b < NBUCK; b += blockDim.x) {
        if (h[b] > 0) base[b] = atomicAdd(&bcursor[b], h[b]);
        h[b] = 0;  // reuse as local rank counter
    }
    __syncthreads();
    for (int i = tid; i < ne; i += blockDim.x) {
        int d = sD[i];
        int b = d >> 9;
        int r = atomicAdd(&h[b], 1);
        int pos = base[b] + r;
        if (pos < CAPB)  // memory-safety clamp; never taken for this input
            epk[b * CAPB + pos] = ((d & 511) << 17) | sS[i];
    }
}

// Per-bucket CSR finalize FUSED with x@W1: per-node counts+scan in LDS,
// rs/re & dis out, LDS-staged col permute + coalesced copy-out, then
// t1h[i][f] = fp16((x[i]@W1)[f] * dis[i]) for the bucket's 512 nodes
// (dis read straight from the LDS histogram).
__global__ __launch_bounds__(512) void k_csr(
        const int* __restrict__ epk, const int* __restrict__ bcursor,
        const float* __restrict__ x, const float* __restrict__ W1,
        int* __restrict__ rs, int* __restrict__ re,
        float* __restrict__ dis, int* __restrict__ colp,
        __half* __restrict__ t1h) {
    __shared__ int hcnt[512];
    __shared__ int s[512];
    __shared__ int lcur[512];
    __shared__ float W1s[F * F];
    __shared__ int colseg[CAPB];
    int b = blockIdx.x;
    int tid = threadIdx.x;
    int n0 = b << 9;
    int nn = min(512, N - n0);
    int cbase = b * CAPB;
    int cnt = min(bcursor[b], CAPB);
    hcnt[tid] = 0;
    for (int i = tid; i < F * F; i += 512) W1s[i] = W1[i];
    __syncthreads();
    for (int i = tid; i < cnt; i += 512)
        atomicAdd(&hcnt[epk[cbase + i] >> 17], 1);
    __syncthreads();
    s[tid] = hcnt[tid];
    __syncthreads();
    for (int off = 1; off < 512; off <<= 1) {
        int t = (tid >= off) ? s[tid - off] : 0;
        __syncthreads();
        s[tid] += t;
        __syncthreads();
    }
    int excl = s[tid] - hcnt[tid];
    lcur[tid] = excl;
    if (tid < nn) {
        rs[n0 + tid] = cbase + excl;
        re[n0 + tid] = cbase + excl + hcnt[tid];
        dis[n0 + tid] = rsqrtf((float)(hcnt[tid] + 1));  // +1 self-loop
    }
    __syncthreads();
    for (int i = tid; i < cnt; i += 512) {
        int p = epk[cbase + i];
        int r = atomicAdd(&lcur[p >> 17], 1);
        colseg[r] = p & 0x1FFFF;
    }
    __syncthreads();
    for (int i = tid; i < cnt; i += 512) colp[cbase + i] = colseg[i];
    // ---- fused x@W1 for this bucket's nodes (hcnt intact) ----
    int g = tid >> 5;       // 16 groups of 32 lanes
    int lane = tid & 31;
    for (int it = 0; it < 32; ++it) {
        int ln = (g << 5) + it;  // local node 0..511
        if (ln < nn) {
            float xv = x[(size_t)(n0 + ln) * F + lane];
            float acc = 0.f;
#pragma unroll
            for (int k = 0; k < F; ++k)
                acc += __shfl(xv, k, 32) * W1s[k * F + lane];
            float d = rsqrtf((float)(hcnt[ln] + 1));
            float v = acc * d;
            float o = __shfl_xor(v, 1, 32);
            if (!(lane & 1))
                ((__half2*)t1h)[(size_t)(n0 + ln) * 16 + (lane >> 1)] =
                    __floats2half2_rn(v, o);
        }
    }
}

// Accumulate one 16B row-slice of fp16 (8 halves) into two float4 accs.
__device__ __forceinline__ void acc8(float4& lo, float4& hi, const float4& r) {
    const __half2* hp = (const __half2*)&r;
    float2 f0 = __half22float2(hp[0]);
    float2 f1 = __half22float2(hp[1]);
    float2 f2 = __half22float2(hp[2]);
    float2 f3 = __half22float2(hp[3]);
    lo.x += f0.x; lo.y += f0.y; lo.z += f1.x; lo.w += f1.y;
    hi.x += f2.x; hi.y += f2.y; hi.z += f3.x; hi.w += f3.y;
}

// Layer-1 aggregation fused with relu/bias and h@W2. 4 lanes per node; each
// lane owns 8 features (16B float4 of fp16). Two cache-blocked passes over
// the edge list (src<SPLIT, src>=SPLIT) keep the gather working set at
// 3.2MB < 4MB per-XCD L2. Loads stay unconditional (fallback = own row,
// cache-hot); accumulate is predicated. Up to 64 lines in flight per wave.
__global__ void k_agg1(const int* __restrict__ rs, const int* __restrict__ re,
                       const int* __restrict__ colp, const __half* __restrict__ t1h,
                       const float* __restrict__ dis, const float* __restrict__ b1,
                       const float* __restrict__ W2, float* __restrict__ t2) {
    int tid = blockIdx.x * blockDim.x + threadIdx.x;
    int node = tid >> 2;
    if (node >= N) return;
    int lane = tid & 3;
    const float4* t1v = (const float4*)t1h;  // 4 float4 (= 8 halves) per row
    int start = rs[node], end = re[node];
    float4 lo0 = {0,0,0,0}, hi0 = {0,0,0,0};
    float4 lo1 = {0,0,0,0}, hi1 = {0,0,0,0};
    float4 lo2 = {0,0,0,0}, hi2 = {0,0,0,0};
    float4 lo3 = {0,0,0,0}, hi3 = {0,0,0,0};
#pragma unroll 1
    for (int pass = 0; pass < 2; ++pass) {
        unsigned LO = pass ? SPLIT : 0u;
        unsigned RG = pass ? (unsigned)(N - SPLIT) : (unsigned)SPLIT;
        for (int base = start; base < end; base += 4) {
            int idx = base + lane;
            int sv = (idx < end) ? colp[idx] : -1;
            int i0 = __shfl(sv, 0, 4);
            int i1 = __shfl(sv, 1, 4);
            int i2 = __shfl(sv, 2, 4);
            int i3 = __shfl(sv, 3, 4);
            bool c0 = (unsigned)(i0 - LO) < RG;
            bool c1 = (unsigned)(i1 - LO) < RG;
            bool c2 = (unsigned)(i2 - LO) < RG;
            bool c3 = (unsigned)(i3 - LO) < RG;
            int j0 = c0 ? i0 : node;
            int j1 = c1 ? i1 : node;
            int j2 = c2 ? i2 : node;
            int j3 = c3 ? i3 : node;
            float4 r0 = t1v[j0 * 4 + lane];
            float4 r1 = t1v[j1 * 4 + lane];
            float4 r2 = t1v[j2 * 4 + lane];
            float4 r3 = t1v[j3 * 4 + lane];
            if (c0) acc8(lo0, hi0, r0);
            if (c1) acc8(lo1, hi1, r1);
            if (c2) acc8(lo2, hi2, r2);
            if (c3) acc8(lo3, hi3, r3);
        }
    }
    float4 alo, ahi;
    alo.x = (lo0.x + lo1.x) + (lo2.x + lo3.x);
    alo.y = (lo0.y + lo1.y) + (lo2.y + lo3.y);
    alo.z = (lo0.z + lo1.z) + (lo2.z + lo3.z);
    alo.w = (lo0.w + lo1.w) + (lo2.w + lo3.w);
    ahi.x = (hi0.x + hi1.x) + (hi2.x + hi3.x);
    ahi.y = (hi0.y + hi1.y) + (hi2.y + hi3.y);
    ahi.z = (hi0.z + hi1.z) + (hi2.z + hi3.z);
    ahi.w = (hi0.w + hi1.w) + (hi2.w + hi3.w);
    float4 wself = t1v[node * 4 + lane];
    const __half2* sp = (const __half2*)&wself;
    float2 s0 = __half22float2(sp[0]);
    float2 s1 = __half22float2(sp[1]);
    float2 s2 = __half22float2(sp[2]);
    float2 s3 = __half22float2(sp[3]);
    float d = dis[node];
    int f0 = 8 * lane;
    float4 b1lo = *(const float4*)(b1 + f0);
    float4 b1hi = *(const float4*)(b1 + f0 + 4);
    float h0 = fmaxf(d * (alo.x + s0.x) + b1lo.x, 0.f);
    float h1 = fmaxf(d * (alo.y + s0.y) + b1lo.y, 0.f);
    float h2 = fmaxf(d * (alo.z + s1.x) + b1lo.z, 0.f);
    float h3 = fmaxf(d * (alo.w + s1.y) + b1lo.w, 0.f);
    float h4 = fmaxf(d * (ahi.x + s2.x) + b1hi.x, 0.f);
    float h5 = fmaxf(d * (ahi.y + s2.y) + b1hi.y, 0.f);
    float h6 = fmaxf(d * (ahi.z + s3.x) + b1hi.z, 0.f);
    float h7 = fmaxf(d * (ahi.w + s3.y) + b1hi.w, 0.f);
    const float4* w2v = (const float4*)W2;  // pairs of rows: [c0,c1,c0,c1]
    float4 q0 = w2v[4 * lane + 0];
    float4 q1 = w2v[4 * lane + 1];
    float4 q2 = w2v[4 * lane + 2];
    float4 q3 = w2v[4 * lane + 3];
    float p0 = h0 * q0.x + h1 * q0.z + h2 * q1.x + h3 * q1.z +
               h4 * q2.x + h5 * q2.z + h6 * q3.x + h7 * q3.z;
    float p1 = h0 * q0.y + h1 * q0.w + h2 * q1.y + h3 * q1.w +
               h4 * q2.y + h5 * q2.w + h6 * q3.y + h7 * q3.w;
    p0 += __shfl_xor(p0, 1, 4);
    p0 += __shfl_xor(p0, 2, 4);
    p1 += __shfl_xor(p1, 1, 4);
    p1 += __shfl_xor(p1, 2, 4);
    if (lane == 0) {
        float2 o;
        o.x = p0 * d;
        o.y = p1 * d;
        *(float2*)(t2 + node * C) = o;
    }
}

// Layer-2 aggregation + bias + log_softmax. 16 lanes per node; t2 (0.8MB) is
// L2-resident on every XCD.
__global__ void k_agg2(const int* __restrict__ rs, const int* __restrict__ re,
                       const int* __restrict__ colp, const float* __restrict__ t2,
                       const float* __restrict__ dis, const float* __restrict__ b2,
                       float* __restrict__ out) {
    int tid = blockIdx.x * blockDim.x + threadIdx.x;
    int node = tid >> 4;
    if (node >= N) return;
    int lane = tid & 15;
    int start = rs[node], end = re[node];
    float a0 = 0.f, a1 = 0.f;
    for (int idx = start + lane; idx < end; idx += 16) {
        int s = colp[idx];
        float2 v = *(const float2*)(t2 + s * C);
        a0 += v.x;
        a1 += v.y;
    }
#pragma unroll
    for (int off = 8; off > 0; off >>= 1) {
        a0 += __shfl_xor(a0, off, 16);
        a1 += __shfl_xor(a1, off, 16);
    }
    if (lane == 0) {
        float d = dis[node];
        float2 self = *(const float2*)(t2 + node * C);
        float z0 = d * (a0 + self.x) + b2[0];
        float z1 = d * (a1 + self.y) + b2[1];
        float m = fmaxf(z0, z1);
        float l = m + logf(expf(z0 - m) + expf(z1 - m));
        float2 o;
        o.x = z0 - l;
        o.y = z1 - l;
        *(float2*)(out + node * C) = o;
    }
}

extern "C" void kernel_launch(void* const* d_in, const int* in_sizes, int n_in,
                              void* d_out, int out_size, void* d_ws, size_t ws_size,
                              hipStream_t stream) {
    const float* x  = (const float*)d_in[0];
    const int*   ei = (const int*)d_in[1];
    const float* W1 = (const float*)d_in[2];
    const float* b1 = (const float*)d_in[3];
    const float* W2 = (const float*)d_in[4];
    const float* b2 = (const float*)d_in[5];
    float* out = (float*)d_out;

    // Workspace (4B units), no overlays:
    // epk[NBUCK*CAPB] | colp[NBUCK*CAPB] | rs[N] | re[N] | dis[N] |
    // t1h[N*F halves] | t2[N*C] | bcursor[NBUCK]
    int* ws_i = (int*)d_ws;
    int*    epk     = ws_i;
    int*    colp    = epk + (size_t)NBUCK * CAPB;
    int*    rs      = colp + (size_t)NBUCK * CAPB;
    int*    re      = rs + N;
    float*  dis     = (float*)(re + N);
    __half* t1h     = (__half*)(dis + N);
    float*  t2      = (float*)(t1h + (size_t)N * F);
    int*    bcursor = (int*)(t2 + (size_t)N * C);

    const int B = 256;
    hipMemsetAsync(bcursor, 0, NBUCK * sizeof(int), stream);
    k_bucket<<<NCHUNK, B, 0, stream>>>(ei, bcursor, epk);
    k_csr<<<NBUCK, 512, 0, stream>>>(epk, bcursor, x, W1, rs, re, dis, colp, t1h);
    k_agg1<<<(N * 4 + B - 1) / B, B, 0, stream>>>(rs, re, colp, t1h, dis, b1, W2, t2);
    k_agg2<<<(N * 16 + B - 1) / B, B, 0, stream>>>(rs, re, colp, t2, dis, b2, out);
}

// Round 10
// 109.946 us; speedup vs baseline: 1.0379x; 1.0379x over previous
//
#include <hip/hip_runtime.h>
#include <hip/hip_fp16.h>
#include <math.h>

constexpr int N = 100000;   // nodes
constexpr int E = 1600000;  // edges
constexpr int F = 32;       // F_IN == HIDDEN
constexpr int C = 2;        // classes

constexpr int NBUCK = (N + 511) >> 9;           // 196 buckets of 512 dst nodes
constexpr int CAPB  = 10240;                    // padded per-bucket capacity
                                                // (mean 8163, sigma ~90 -> +23 sigma)
constexpr int CHUNK = 8192;                     // edges per redistribution WG
constexpr int NCHUNK = (E + CHUNK - 1) / CHUNK; // 196
constexpr int SPLIT = 50000;                    // agg1 cache-blocking split (3.2MB halves)

__device__ __forceinline__ int get_src(const int* ei, int e, int f64) {
    return f64 ? ei[2 * e] : ei[e];
}
__device__ __forceinline__ int get_dst(const int* ei, int e, int f64) {
    return f64 ? ei[2 * (E + e)] : ei[E + e];
}

// ---------------------------------------------------------------------------
// Bucket redistribution with built-in int64/int32 layout probe (all-zero odd
// dwords over 2048 samples <=> int64 little-endian; impossible for random
// int32 in [0,100000)). Chunk staged in LDS; one global atomic per
// (WG, bucket); writes form ~196 sequential streams into padded bucket slots.
// ---------------------------------------------------------------------------
__global__ void k_bucket(const int* __restrict__ ei, int* __restrict__ bcursor,
                         int* __restrict__ epk) {
    __shared__ int h[NBUCK];
    __shared__ int base[NBUCK];
    __shared__ int sS[CHUNK];
    __shared__ int sD[CHUNK];
    __shared__ int sflag;
    int tid = threadIdx.x;
    if (tid == 0) sflag = 0;
    for (int i = tid; i < NBUCK; i += blockDim.x) h[i] = 0;
    __syncthreads();
    int accf = 0;
    for (int i = tid; i < 2048; i += blockDim.x) accf |= ei[2 * i + 1];
    if (accf) atomicOr(&sflag, 1);
    __syncthreads();
    int f64 = sflag ? 0 : 1;
    int e0 = blockIdx.x * CHUNK;
    int ne = min(E - e0, CHUNK);
    for (int i = tid; i < ne; i += blockDim.x) {
        int s = get_src(ei, e0 + i, f64);
        int d = get_dst(ei, e0 + i, f64);
        sS[i] = s;
        sD[i] = d;
        atomicAdd(&h[d >> 9], 1);
    }
    __syncthreads();
    for (int b = tid; b < NBUCK; b += blockDim.x) {
        if (h[b] > 0) base[b] = atomicAdd(&bcursor[b], h[b]);
        h[b] = 0;  // reuse as local rank counter
    }
    __syncthreads();
    for (int i = tid; i < ne; i += blockDim.x) {
        int d = sD[i];
        int b = d >> 9;
        int r = atomicAdd(&h[b], 1);
        int pos = base[b] + r;
        if (pos < CAPB)  // memory-safety clamp; never taken for this input
            epk[b * CAPB + pos] = ((d & 511) << 17) | sS[i];
    }
}

// Per-bucket CSR finalize: per-node counts+scan in LDS, rs/re & dis out,
// LDS-staged col permute, coalesced copy-out into padded col array.
__global__ __launch_bounds__(512) void k_csr(
        const int* __restrict__ epk, const int* __restrict__ bcursor,
        int* __restrict__ rs, int* __restrict__ re,
        float* __restrict__ dis, int* __restrict__ colp) {
    __shared__ int hcnt[512];
    __shared__ int s[512];
    __shared__ int lcur[512];
    __shared__ int colseg[CAPB];
    int b = blockIdx.x;
    int tid = threadIdx.x;
    int n0 = b << 9;
    int nn = min(512, N - n0);
    int cbase = b * CAPB;
    int cnt = min(bcursor[b], CAPB);
    hcnt[tid] = 0;
    __syncthreads();
    for (int i = tid; i < cnt; i += 512)
        atomicAdd(&hcnt[epk[cbase + i] >> 17], 1);
    __syncthreads();
    s[tid] = hcnt[tid];
    __syncthreads();
    for (int off = 1; off < 512; off <<= 1) {
        int t = (tid >= off) ? s[tid - off] : 0;
        __syncthreads();
        s[tid] += t;
        __syncthreads();
    }
    int excl = s[tid] - hcnt[tid];
    lcur[tid] = excl;
    if (tid < nn) {
        rs[n0 + tid] = cbase + excl;
        re[n0 + tid] = cbase + excl + hcnt[tid];
        dis[n0 + tid] = rsqrtf((float)(hcnt[tid] + 1));  // +1 self-loop
    }
    __syncthreads();
    for (int i = tid; i < cnt; i += 512) {
        int p = epk[cbase + i];
        int r = atomicAdd(&lcur[p >> 17], 1);
        colseg[r] = p & 0x1FFFF;
    }
    __syncthreads();
    for (int i = tid; i < cnt; i += 512) colp[cbase + i] = colseg[i];
}

// t1h[i][f] = fp16( (x[i] @ W1)[f] * dis[i] ).  32 lanes per node; x row is
// loaded coalesced (1 float/lane) and broadcast via shfl.
__global__ void k_xw1(const float* __restrict__ x, const float* __restrict__ W1,
                      const float* __restrict__ dis, __half* __restrict__ t1h) {
    __shared__ float W1s[F * F];
    int tid = threadIdx.x;
    for (int i = tid; i < F * F; i += blockDim.x) W1s[i] = W1[i];
    __syncthreads();
    int lane = tid & 31;
    int node = (blockIdx.x * blockDim.x + tid) >> 5;
    if (node >= N) return;
    float xv = x[node * F + lane];
    float acc = 0.f;
#pragma unroll
    for (int k = 0; k < F; ++k) acc += __shfl(xv, k, 32) * W1s[k * F + lane];
    float v = acc * dis[node];
    float o = __shfl_xor(v, 1, 32);
    if (!(lane & 1))
        ((__half2*)t1h)[node * 16 + (lane >> 1)] = __floats2half2_rn(v, o);
}

// Accumulate one 16B row-slice of fp16 (8 halves) into two float4 accs.
__device__ __forceinline__ void acc8(float4& lo, float4& hi, const float4& r) {
    const __half2* hp = (const __half2*)&r;
    float2 f0 = __half22float2(hp[0]);
    float2 f1 = __half22float2(hp[1]);
    float2 f2 = __half22float2(hp[2]);
    float2 f3 = __half22float2(hp[3]);
    lo.x += f0.x; lo.y += f0.y; lo.z += f1.x; lo.w += f1.y;
    hi.x += f2.x; hi.y += f2.y; hi.z += f3.x; hi.w += f3.y;
}

// Layer-1 aggregation fused with relu/bias and h@W2. 4 lanes per node; each
// lane owns 8 features (16B float4 of fp16). Two cache-blocked passes over
// the edge list (src<SPLIT, src>=SPLIT) keep the gather working set at
// 3.2MB < 4MB per-XCD L2. Loads stay unconditional (fallback = own row,
// cache-hot); accumulate is predicated. Up to 64 lines in flight per wave.
__global__ void k_agg1(const int* __restrict__ rs, const int* __restrict__ re,
                       const int* __restrict__ colp, const __half* __restrict__ t1h,
                       const float* __restrict__ dis, const float* __restrict__ b1,
                       const float* __restrict__ W2, float* __restrict__ t2) {
    int tid = blockIdx.x * blockDim.x + threadIdx.x;
    int node = tid >> 2;
    if (node >= N) return;
    int lane = tid & 3;
    const float4* t1v = (const float4*)t1h;  // 4 float4 (= 8 halves) per row
    int start = rs[node], end = re[node];
    float4 lo0 = {0,0,0,0}, hi0 = {0,0,0,0};
    float4 lo1 = {0,0,0,0}, hi1 = {0,0,0,0};
    float4 lo2 = {0,0,0,0}, hi2 = {0,0,0,0};
    float4 lo3 = {0,0,0,0}, hi3 = {0,0,0,0};
#pragma unroll 1
    for (int pass = 0; pass < 2; ++pass) {
        unsigned LO = pass ? SPLIT : 0u;
        unsigned RG = pass ? (unsigned)(N - SPLIT) : (unsigned)SPLIT;
        for (int base = start; base < end; base += 4) {
            int idx = base + lane;
            int sv = (idx < end) ? colp[idx] : -1;
            int i0 = __shfl(sv, 0, 4);
            int i1 = __shfl(sv, 1, 4);
            int i2 = __shfl(sv, 2, 4);
            int i3 = __shfl(sv, 3, 4);
            bool c0 = (unsigned)(i0 - LO) < RG;
            bool c1 = (unsigned)(i1 - LO) < RG;
            bool c2 = (unsigned)(i2 - LO) < RG;
            bool c3 = (unsigned)(i3 - LO) < RG;
            int j0 = c0 ? i0 : node;
            int j1 = c1 ? i1 : node;
            int j2 = c2 ? i2 : node;
            int j3 = c3 ? i3 : node;
            float4 r0 = t1v[j0 * 4 + lane];
            float4 r1 = t1v[j1 * 4 + lane];
            float4 r2 = t1v[j2 * 4 + lane];
            float4 r3 = t1v[j3 * 4 + lane];
            if (c0) acc8(lo0, hi0, r0);
            if (c1) acc8(lo1, hi1, r1);
            if (c2) acc8(lo2, hi2, r2);
            if (c3) acc8(lo3, hi3, r3);
        }
    }
    float4 alo, ahi;
    alo.x = (lo0.x + lo1.x) + (lo2.x + lo3.x);
    alo.y = (lo0.y + lo1.y) + (lo2.y + lo3.y);
    alo.z = (lo0.z + lo1.z) + (lo2.z + lo3.z);
    alo.w = (lo0.w + lo1.w) + (lo2.w + lo3.w);
    ahi.x = (hi0.x + hi1.x) + (hi2.x + hi3.x);
    ahi.y = (hi0.y + hi1.y) + (hi2.y + hi3.y);
    ahi.z = (hi0.z + hi1.z) + (hi2.z + hi3.z);
    ahi.w = (hi0.w + hi1.w) + (hi2.w + hi3.w);
    float4 wself = t1v[node * 4 + lane];
    const __half2* sp = (const __half2*)&wself;
    float2 s0 = __half22float2(sp[0]);
    float2 s1 = __half22float2(sp[1]);
    float2 s2 = __half22float2(sp[2]);
    float2 s3 = __half22float2(sp[3]);
    float d = dis[node];
    int f0 = 8 * lane;
    float4 b1lo = *(const float4*)(b1 + f0);
    float4 b1hi = *(const float4*)(b1 + f0 + 4);
    float h0 = fmaxf(d * (alo.x + s0.x) + b1lo.x, 0.f);
    float h1 = fmaxf(d * (alo.y + s0.y) + b1lo.y, 0.f);
    float h2 = fmaxf(d * (alo.z + s1.x) + b1lo.z, 0.f);
    float h3 = fmaxf(d * (alo.w + s1.y) + b1lo.w, 0.f);
    float h4 = fmaxf(d * (ahi.x + s2.x) + b1hi.x, 0.f);
    float h5 = fmaxf(d * (ahi.y + s2.y) + b1hi.y, 0.f);
    float h6 = fmaxf(d * (ahi.z + s3.x) + b1hi.z, 0.f);
    float h7 = fmaxf(d * (ahi.w + s3.y) + b1hi.w, 0.f);
    const float4* w2v = (const float4*)W2;  // pairs of rows: [c0,c1,c0,c1]
    float4 q0 = w2v[4 * lane + 0];
    float4 q1 = w2v[4 * lane + 1];
    float4 q2 = w2v[4 * lane + 2];
    float4 q3 = w2v[4 * lane + 3];
    float p0 = h0 * q0.x + h1 * q0.z + h2 * q1.x + h3 * q1.z +
               h4 * q2.x + h5 * q2.z + h6 * q3.x + h7 * q3.z;
    float p1 = h0 * q0.y + h1 * q0.w + h2 * q1.y + h3 * q1.w +
               h4 * q2.y + h5 * q2.w + h6 * q3.y + h7 * q3.w;
    p0 += __shfl_xor(p0, 1, 4);
    p0 += __shfl_xor(p0, 2, 4);
    p1 += __shfl_xor(p1, 1, 4);
    p1 += __shfl_xor(p1, 2, 4);
    if (lane == 0) {
        float2 o;
        o.x = p0 * d;
        o.y = p1 * d;
        *(float2*)(t2 + node * C) = o;
    }
}

// Layer-2 aggregation + bias + log_softmax. 16 lanes per node; t2 (0.8MB) is
// L2-resident on every XCD.
__global__ void k_agg2(const int* __restrict__ rs, const int* __restrict__ re,
                       const int* __restrict__ colp, const float* __restrict__ t2,
                       const float* __restrict__ dis, const float* __restrict__ b2,
                       float* __restrict__ out) {
    int tid = blockIdx.x * blockDim.x + threadIdx.x;
    int node = tid >> 4;
    if (node >= N) return;
    int lane = tid & 15;
    int start = rs[node], end = re[node];
    float a0 = 0.f, a1 = 0.f;
    for (int idx = start + lane; idx < end; idx += 16) {
        int s = colp[idx];
        float2 v = *(const float2*)(t2 + s * C);
        a0 += v.x;
        a1 += v.y;
    }
#pragma unroll
    for (int off = 8; off > 0; off >>= 1) {
        a0 += __shfl_xor(a0, off, 16);
        a1 += __shfl_xor(a1, off, 16);
    }
    if (lane == 0) {
        float d = dis[node];
        float2 self = *(const float2*)(t2 + node * C);
        float z0 = d * (a0 + self.x) + b2[0];
        float z1 = d * (a1 + self.y) + b2[1];
        float m = fmaxf(z0, z1);
        float l = m + logf(expf(z0 - m) + expf(z1 - m));
        float2 o;
        o.x = z0 - l;
        o.y = z1 - l;
        *(float2*)(out + node * C) = o;
    }
}

extern "C" void kernel_launch(void* const* d_in, const int* in_sizes, int n_in,
                              void* d_out, int out_size, void* d_ws, size_t ws_size,
                              hipStream_t stream) {
    const float* x  = (const float*)d_in[0];
    const int*   ei = (const int*)d_in[1];
    const float* W1 = (const float*)d_in[2];
    const float* b1 = (const float*)d_in[3];
    const float* W2 = (const float*)d_in[4];
    const float* b2 = (const float*)d_in[5];
    float* out = (float*)d_out;

    // Workspace (4B units), no overlays:
    // epk[NBUCK*CAPB] | colp[NBUCK*CAPB] | rs[N] | re[N] | dis[N] |
    // t1h[N*F halves] | t2[N*C] | bcursor[NBUCK]
    int* ws_i = (int*)d_ws;
    int*    epk     = ws_i;
    int*    colp    = epk + (size_t)NBUCK * CAPB;
    int*    rs      = colp + (size_t)NBUCK * CAPB;
    int*    re      = rs + N;
    float*  dis     = (float*)(re + N);
    __half* t1h     = (__half*)(dis + N);
    float*  t2      = (float*)(t1h + (size_t)N * F);
    int*    bcursor = (int*)(t2 + (size_t)N * C);

    const int B = 256;
    hipMemsetAsync(bcursor, 0, NBUCK * sizeof(int), stream);
    k_bucket<<<NCHUNK, B, 0, stream>>>(ei, bcursor, epk);
    k_csr<<<NBUCK, 512, 0, stream>>>(epk, bcursor, rs, re, dis, colp);
    k_xw1<<<(N * 32 + B - 1) / B, B, 0, stream>>>(x, W1, dis, t1h);
    k_agg1<<<(N * 4 + B - 1) / B, B, 0, stream>>>(rs, re, colp, t1h, dis, b1, W2, t2);
    k_agg2<<<(N * 16 + B - 1) / B, B, 0, stream>>>(rs, re, colp, t2, dis, b2, out);
}

// Round 11
// 108.333 us; speedup vs baseline: 1.0534x; 1.0149x over previous
//
#include <hip/hip_runtime.h>
#include <hip/hip_fp16.h>
#include <math.h>

constexpr int N = 100000;   // nodes
constexpr int E = 1600000;  // edges
constexpr int F = 32;       // F_IN == HIDDEN
constexpr int C = 2;        // classes

constexpr int NBUCK = (N + 511) >> 9;           // 196 buckets of 512 dst nodes
constexpr int CAPB  = 10240;                    // padded per-bucket capacity
                                                // (mean 8163, sigma ~90 -> +23 sigma)
constexpr int CHUNK = 8192;                     // edges per redistribution WG
constexpr int NCHUNK = (E + CHUNK - 1) / CHUNK; // 196

__device__ __forceinline__ int get_src(const int* ei, int e, int f64) {
    return f64 ? ei[2 * e] : ei[e];
}
__device__ __forceinline__ int get_dst(const int* ei, int e, int f64) {
    return f64 ? ei[2 * (E + e)] : ei[E + e];
}

// ---------------------------------------------------------------------------
// Bucket redistribution with built-in int64/int32 layout probe (all-zero odd
// dwords over 2048 samples <=> int64 little-endian; impossible for random
// int32 in [0,100000)). Chunk staged in LDS; one global atomic per
// (WG, bucket); writes form ~196 sequential streams into padded bucket slots.
// ---------------------------------------------------------------------------
__global__ void k_bucket(const int* __restrict__ ei, int* __restrict__ bcursor,
                         int* __restrict__ epk) {
    __shared__ int h[NBUCK];
    __shared__ int base[NBUCK];
    __shared__ int sS[CHUNK];
    __shared__ int sD[CHUNK];
    __shared__ int sflag;
    int tid = threadIdx.x;
    if (tid == 0) sflag = 0;
    for (int i = tid; i < NBUCK; i += blockDim.x) h[i] = 0;
    __syncthreads();
    int accf = 0;
    for (int i = tid; i < 2048; i += blockDim.x) accf |= ei[2 * i + 1];
    if (accf) atomicOr(&sflag, 1);
    __syncthreads();
    int f64 = sflag ? 0 : 1;
    int e0 = blockIdx.x * CHUNK;
    int ne = min(E - e0, CHUNK);
    for (int i = tid; i < ne; i += blockDim.x) {
        int s = get_src(ei, e0 + i, f64);
        int d = get_dst(ei, e0 + i, f64);
        sS[i] = s;
        sD[i] = d;
        atomicAdd(&h[d >> 9], 1);
    }
    __syncthreads();
    for (int b = tid; b < NBUCK; b += blockDim.x) {
        if (h[b] > 0) base[b] = atomicAdd(&bcursor[b], h[b]);
        h[b] = 0;  // reuse as local rank counter
    }
    __syncthreads();
    for (int i = tid; i < ne; i += blockDim.x) {
        int d = sD[i];
        int b = d >> 9;
        int r = atomicAdd(&h[b], 1);
        int pos = base[b] + r;
        if (pos < CAPB)  // memory-safety clamp; never taken for this input
            epk[b * CAPB + pos] = ((d & 511) << 17) | sS[i];
    }
}

// Per-bucket CSR finalize: per-node counts+scan in LDS, rs/re & dis out,
// LDS-staged col permute, coalesced copy-out into padded col array.
__global__ __launch_bounds__(512) void k_csr(
        const int* __restrict__ epk, const int* __restrict__ bcursor,
        int* __restrict__ rs, int* __restrict__ re,
        float* __restrict__ dis, int* __restrict__ colp) {
    __shared__ int hcnt[512];
    __shared__ int s[512];
    __shared__ int lcur[512];
    __shared__ int colseg[CAPB];
    int b = blockIdx.x;
    int tid = threadIdx.x;
    int n0 = b << 9;
    int nn = min(512, N - n0);
    int cbase = b * CAPB;
    int cnt = min(bcursor[b], CAPB);
    hcnt[tid] = 0;
    __syncthreads();
    for (int i = tid; i < cnt; i += 512)
        atomicAdd(&hcnt[epk[cbase + i] >> 17], 1);
    __syncthreads();
    s[tid] = hcnt[tid];
    __syncthreads();
    for (int off = 1; off < 512; off <<= 1) {
        int t = (tid >= off) ? s[tid - off] : 0;
        __syncthreads();
        s[tid] += t;
        __syncthreads();
    }
    int excl = s[tid] - hcnt[tid];
    lcur[tid] = excl;
    if (tid < nn) {
        rs[n0 + tid] = cbase + excl;
        re[n0 + tid] = cbase + excl + hcnt[tid];
        dis[n0 + tid] = rsqrtf((float)(hcnt[tid] + 1));  // +1 self-loop
    }
    __syncthreads();
    for (int i = tid; i < cnt; i += 512) {
        int p = epk[cbase + i];
        int r = atomicAdd(&lcur[p >> 17], 1);
        colseg[r] = p & 0x1FFFF;
    }
    __syncthreads();
    for (int i = tid; i < cnt; i += 512) colp[cbase + i] = colseg[i];
}

// t1h[i][f] = fp16( (x[i] @ W1)[f] * dis[i] ).  32 lanes per node; x row is
// loaded coalesced (1 float/lane) and broadcast via shfl.
__global__ void k_xw1(const float* __restrict__ x, const float* __restrict__ W1,
                      const float* __restrict__ dis, __half* __restrict__ t1h) {
    __shared__ float W1s[F * F];
    int tid = threadIdx.x;
    for (int i = tid; i < F * F; i += blockDim.x) W1s[i] = W1[i];
    __syncthreads();
    int lane = tid & 31;
    int node = (blockIdx.x * blockDim.x + tid) >> 5;
    if (node >= N) return;
    float xv = x[node * F + lane];
    float acc = 0.f;
#pragma unroll
    for (int k = 0; k < F; ++k) acc += __shfl(xv, k, 32) * W1s[k * F + lane];
    float v = acc * dis[node];
    float o = __shfl_xor(v, 1, 32);
    if (!(lane & 1))
        ((__half2*)t1h)[node * 16 + (lane >> 1)] = __floats2half2_rn(v, o);
}

// Accumulate one 16B row-slice (4 half2) into 4 packed-half2 accumulators.
__device__ __forceinline__ void acch(__half2 (&a)[4], const float4& r) {
    const __half2* hp = (const __half2*)&r;
    a[0] = __hadd2(a[0], hp[0]);
    a[1] = __hadd2(a[1], hp[1]);
    a[2] = __hadd2(a[2], hp[2]);
    a[3] = __hadd2(a[3], hp[3]);
}

// Layer-1 aggregation fused with relu/bias and h@W2. 4 lanes per node; each
// lane owns 8 features (16B float4 of fp16). 4-deep unrolled gathers with
// per-slot packed-half2 accumulation (v_pk_add_f16: 4 VALU per 16B vs 16).
// Each slot sums ~deg/4 terms in fp16 (tiny error); slots are combined in
// fp32. Up to 64 cache lines in flight per wave.
__global__ void k_agg1(const int* __restrict__ rs, const int* __restrict__ re,
                       const int* __restrict__ colp, const __half* __restrict__ t1h,
                       const float* __restrict__ dis, const float* __restrict__ b1,
                       const float* __restrict__ W2, float* __restrict__ t2) {
    int tid = blockIdx.x * blockDim.x + threadIdx.x;
    int node = tid >> 2;
    if (node >= N) return;
    int lane = tid & 3;
    const float4* t1v = (const float4*)t1h;  // 4 float4 (= 8 halves) per row
    int start = rs[node], end = re[node];
    __half2 z = __floats2half2_rn(0.f, 0.f);
    __half2 a0[4] = {z, z, z, z};
    __half2 a1[4] = {z, z, z, z};
    __half2 a2[4] = {z, z, z, z};
    __half2 a3[4] = {z, z, z, z};
    for (int base = start; base < end; base += 4) {
        int idx = base + lane;
        int sv = (idx < end) ? colp[idx] : 0;
        int cnt = end - base;
        if (cnt >= 4) {
            int i0 = __shfl(sv, 0, 4);
            int i1 = __shfl(sv, 1, 4);
            int i2 = __shfl(sv, 2, 4);
            int i3 = __shfl(sv, 3, 4);
            float4 r0 = t1v[i0 * 4 + lane];
            float4 r1 = t1v[i1 * 4 + lane];
            float4 r2 = t1v[i2 * 4 + lane];
            float4 r3 = t1v[i3 * 4 + lane];
            acch(a0, r0);
            acch(a1, r1);
            acch(a2, r2);
            acch(a3, r3);
        } else {
            for (int j = 0; j < cnt; ++j) {
                int ss = __shfl(sv, j, 4);
                float4 r = t1v[ss * 4 + lane];
                acch(a0, r);
            }
        }
    }
    // combine slots in fp32
    float2 f0, f1, f2, f3;
    {
        float2 c0 = __half22float2(a0[0]), c1 = __half22float2(a1[0]);
        float2 c2 = __half22float2(a2[0]), c3 = __half22float2(a3[0]);
        f0.x = (c0.x + c1.x) + (c2.x + c3.x);
        f0.y = (c0.y + c1.y) + (c2.y + c3.y);
    }
    {
        float2 c0 = __half22float2(a0[1]), c1 = __half22float2(a1[1]);
        float2 c2 = __half22float2(a2[1]), c3 = __half22float2(a3[1]);
        f1.x = (c0.x + c1.x) + (c2.x + c3.x);
        f1.y = (c0.y + c1.y) + (c2.y + c3.y);
    }
    {
        float2 c0 = __half22float2(a0[2]), c1 = __half22float2(a1[2]);
        float2 c2 = __half22float2(a2[2]), c3 = __half22float2(a3[2]);
        f2.x = (c0.x + c1.x) + (c2.x + c3.x);
        f2.y = (c0.y + c1.y) + (c2.y + c3.y);
    }
    {
        float2 c0 = __half22float2(a0[3]), c1 = __half22float2(a1[3]);
        float2 c2 = __half22float2(a2[3]), c3 = __half22float2(a3[3]);
        f3.x = (c0.x + c1.x) + (c2.x + c3.x);
        f3.y = (c0.y + c1.y) + (c2.y + c3.y);
    }
    float4 wself = t1v[node * 4 + lane];
    const __half2* sp = (const __half2*)&wself;
    float2 s0 = __half22float2(sp[0]);
    float2 s1 = __half22float2(sp[1]);
    float2 s2 = __half22float2(sp[2]);
    float2 s3 = __half22float2(sp[3]);
    float d = dis[node];
    int fb = 8 * lane;
    float4 b1lo = *(const float4*)(b1 + fb);
    float4 b1hi = *(const float4*)(b1 + fb + 4);
    float h0 = fmaxf(d * (f0.x + s0.x) + b1lo.x, 0.f);
    float h1 = fmaxf(d * (f0.y + s0.y) + b1lo.y, 0.f);
    float h2 = fmaxf(d * (f1.x + s1.x) + b1lo.z, 0.f);
    float h3 = fmaxf(d * (f1.y + s1.y) + b1lo.w, 0.f);
    float h4 = fmaxf(d * (f2.x + s2.x) + b1hi.x, 0.f);
    float h5 = fmaxf(d * (f2.y + s2.y) + b1hi.y, 0.f);
    float h6 = fmaxf(d * (f3.x + s3.x) + b1hi.z, 0.f);
    float h7 = fmaxf(d * (f3.y + s3.y) + b1hi.w, 0.f);
    const float4* w2v = (const float4*)W2;  // pairs of rows: [c0,c1,c0,c1]
    float4 q0 = w2v[4 * lane + 0];
    float4 q1 = w2v[4 * lane + 1];
    float4 q2 = w2v[4 * lane + 2];
    float4 q3 = w2v[4 * lane + 3];
    float p0 = h0 * q0.x + h1 * q0.z + h2 * q1.x + h3 * q1.z +
               h4 * q2.x + h5 * q2.z + h6 * q3.x + h7 * q3.z;
    float p1 = h0 * q0.y + h1 * q0.w + h2 * q1.y + h3 * q1.w +
               h4 * q2.y + h5 * q2.w + h6 * q3.y + h7 * q3.w;
    p0 += __shfl_xor(p0, 1, 4);
    p0 += __shfl_xor(p0, 2, 4);
    p1 += __shfl_xor(p1, 1, 4);
    p1 += __shfl_xor(p1, 2, 4);
    if (lane == 0) {
        float2 o;
        o.x = p0 * d;
        o.y = p1 * d;
        *(float2*)(t2 + node * C) = o;
    }
}

// Layer-2 aggregation + bias + log_softmax. 8 lanes per node (avg degree 16
// -> 2 iters/lane); t2 (0.8MB) is L2-resident on every XCD.
__global__ void k_agg2(const int* __restrict__ rs, const int* __restrict__ re,
                       const int* __restrict__ colp, const float* __restrict__ t2,
                       const float* __restrict__ dis, const float* __restrict__ b2,
                       float* __restrict__ out) {
    int tid = blockIdx.x * blockDim.x + threadIdx.x;
    int node = tid >> 3;
    if (node >= N) return;
    int lane = tid & 7;
    int start = rs[node], end = re[node];
    float a0 = 0.f, a1 = 0.f;
    for (int idx = start + lane; idx < end; idx += 8) {
        int s = colp[idx];
        float2 v = *(const float2*)(t2 + s * C);
        a0 += v.x;
        a1 += v.y;
    }
#pragma unroll
    for (int off = 4; off > 0; off >>= 1) {
        a0 += __shfl_xor(a0, off, 8);
        a1 += __shfl_xor(a1, off, 8);
    }
    if (lane == 0) {
        float d = dis[node];
        float2 self = *(const float2*)(t2 + node * C);
        float z0 = d * (a0 + self.x) + b2[0];
        float z1 = d * (a1 + self.y) + b2[1];
        float m = fmaxf(z0, z1);
        float l = m + logf(expf(z0 - m) + expf(z1 - m));
        float2 o;
        o.x = z0 - l;
        o.y = z1 - l;
        *(float2*)(out + node * C) = o;
    }
}

extern "C" void kernel_launch(void* const* d_in, const int* in_sizes, int n_in,
                              void* d_out, int out_size, void* d_ws, size_t ws_size,
                              hipStream_t stream) {
    const float* x  = (const float*)d_in[0];
    const int*   ei = (const int*)d_in[1];
    const float* W1 = (const float*)d_in[2];
    const float* b1 = (const float*)d_in[3];
    const float* W2 = (const float*)d_in[4];
    const float* b2 = (const float*)d_in[5];
    float* out = (float*)d_out;

    // Workspace (4B units), no overlays:
    // epk[NBUCK*CAPB] | colp[NBUCK*CAPB] | rs[N] | re[N] | dis[N] |
    // t1h[N*F halves] | t2[N*C] | bcursor[NBUCK]
    int* ws_i = (int*)d_ws;
    int*    epk     = ws_i;
    int*    colp    = epk + (size_t)NBUCK * CAPB;
    int*    rs      = colp + (size_t)NBUCK * CAPB;
    int*    re      = rs + N;
    float*  dis     = (float*)(re + N);
    __half* t1h     = (__half*)(dis + N);
    float*  t2      = (float*)(t1h + (size_t)N * F);
    int*    bcursor = (int*)(t2 + (size_t)N * C);

    const int B = 256;
    hipMemsetAsync(bcursor, 0, NBUCK * sizeof(int), stream);
    k_bucket<<<NCHUNK, B, 0, stream>>>(ei, bcursor, epk);
    k_csr<<<NBUCK, 512, 0, stream>>>(epk, bcursor, rs, re, dis, colp);
    k_xw1<<<(N * 32 + B - 1) / B, B, 0, stream>>>(x, W1, dis, t1h);
    k_agg1<<<(N * 4 + B - 1) / B, B, 0, stream>>>(rs, re, colp, t1h, dis, b1, W2, t2);
    k_agg2<<<(N * 8 + B - 1) / B, B, 0, stream>>>(rs, re, colp, t2, dis, b2, out);
}